// Round 12
// baseline (441.011 us; speedup 1.0000x reference)
//
#include <hip/hip_runtime.h>
#include <math.h>

#ifndef M_PI
#define M_PI 3.14159265358979323846
#endif

#define T_LEN 4096
#define M_LEN 2048   // T/2, complex FFT length (k_fwd)
#define NFREQ 2049   // T/2 + 1
#define KM 8         // modes
#define LI 8         // iterations
#define CD 16        // channels

// LDS XOR swizzle on float2 index (bijective on [0,4096); validated r4/r11).
#define SWZ(i) ((i) ^ (((i) >> 4) & 15))

// Stockham radix-2 DIF, N=2048, ping-pong (proven k_fwd engine, sign=-1 fwd).
template <int NT>
__device__ __forceinline__ float2* fft2048(float2* a, float2* b, int tid, float sign) {
    float2* src = a;
    float2* dst = b;
    int l = 1024;
    #pragma unroll 1
    for (int s = 0; s < 11; ++s) {
        float piol = sign * (float)M_PI / (float)l;
        #pragma unroll
        for (int ii = 0; ii < 1024 / NT; ++ii) {
            int i = tid + ii * NT;
            int j = i >> s;
            float2 A = src[i];
            float2 B = src[i + 1024];
            float ang = piol * (float)j;
            float sw, cw;
            __sincosf(ang, &sw, &cw);
            float2 sum = make_float2(A.x + B.x, A.y + B.y);
            float2 dif = make_float2(A.x - B.x, A.y - B.y);
            float2 tw = make_float2(dif.x * cw - dif.y * sw, dif.x * sw + dif.y * cw);
            int p = i + (j << s);
            dst[p] = sum;
            dst[p + (1 << s)] = tw;
        }
        __syncthreads();
        float2* t = src; src = dst; dst = t;
        l >>= 1;
    }
    return src;
}

// K1: UNCHANGED from r11 (passed; <=153us). 512 threads, 1 row per block,
// radix-2 FFT + reduced Jacobi (carried SUM(u), h=lambda/2, layer-0 special).
__global__ void __launch_bounds__(512)
k_fwd_iter(const float* __restrict__ x,
           const float* __restrict__ log_alpha,
           const float* __restrict__ raw_tau,
           const float* __restrict__ raw_omega,
           float2* __restrict__ u_ws)
{
    __shared__ float2 bufA[M_LEN];
    __shared__ float2 bufB[M_LEN];
    __shared__ float s_2a[LI * KM];
    __shared__ float s_tau2[LI];      // 0.5 * softplus(raw_tau)
    __shared__ float s_om[KM];

    const int tid = threadIdx.x;
    const int row = blockIdx.x;       // b*16 + c
    const int b = row >> 4;
    const int c = row & 15;

    if (tid < LI * KM) s_2a[tid]   = 2.0f * __expf(log_alpha[tid]);
    if (tid < LI)      s_tau2[tid] = 0.5f * log1pf(__expf(raw_tau[tid]));
    if (tid < KM)      s_om[tid]   = 0.5f / (1.0f + __expf(-raw_omega[tid]));

    const float* xr = x + (size_t)b * T_LEN * CD + c;
    #pragma unroll
    for (int q = 0; q < 4; ++q) {
        int n = tid + q * 512;
        float e = xr[(size_t)(2 * n) * CD];
        float o = xr[(size_t)(2 * n + 1) * CD];
        bufA[n] = make_float2(e, o);
    }
    __syncthreads();

    float2* Z = fft2048<512>(bufA, bufB, tid, -1.0f);   // ends in bufB

    const size_t sb = (size_t)(b * (KM * CD) + c);

    for (int f = tid; f < NFREQ; f += 512) {
        float2 Zk = Z[f & (M_LEN - 1)];
        float2 Zm = Z[(M_LEN - f) & (M_LEN - 1)];
        float2 E = make_float2(0.5f * (Zk.x + Zm.x), 0.5f * (Zk.y - Zm.y));
        float2 D = make_float2(0.5f * (Zk.x - Zm.x), 0.5f * (Zk.y + Zm.y));
        float2 O = make_float2(D.y, -D.x);
        float ang = -2.0f * (float)M_PI * (float)f / (float)T_LEN;
        float sw, cw;
        __sincosf(ang, &sw, &cw);
        float fhx = E.x + cw * O.x - sw * O.y;
        float fhy = E.y + cw * O.y + sw * O.x;

        float freq = (float)f * (0.5f / (float)M_LEN);
        float dd[KM];
        #pragma unroll
        for (int k = 0; k < KM; ++k) {
            float d = freq - s_om[k];
            dd[k] = d * d;
        }

        float2 u[KM];
        float sx, sy;                 // carried SUM(u)
        float hx, hy;                 // 0.5 * lambda

        {
            float nsx = 0.f, nsy = 0.f;
            #pragma unroll
            for (int k = 0; k < KM; ++k) {
                float den = fmaf(s_2a[k], dd[k], 1.0f);
                float r = __builtin_amdgcn_rcpf(den);
                float ux = fhx * r;
                float uy = fhy * r;
                u[k].x = ux; u[k].y = uy;
                nsx += ux; nsy += uy;
            }
            hx = s_tau2[0] * (fhx - nsx);
            hy = s_tau2[0] * (fhy - nsy);
            sx = nsx; sy = nsy;
        }

        #pragma unroll
        for (int l = 1; l < LI; ++l) {
            float bx = fhx - sx + hx;
            float by = fhy - sy + hy;
            float nsx = 0.f, nsy = 0.f;
            #pragma unroll
            for (int k = 0; k < KM; ++k) {
                float den = fmaf(s_2a[l * KM + k], dd[k], 1.0f);
                float r = __builtin_amdgcn_rcpf(den);
                float ux = (bx + u[k].x) * r;
                float uy = (by + u[k].y) * r;
                u[k].x = ux; u[k].y = uy;
                nsx += ux; nsy += uy;
            }
            hx += s_tau2[l] * (fhx - nsx);
            hy += s_tau2[l] * (fhy - nsy);
            sx = nsx; sy = nsy;
        }

        #pragma unroll
        for (int k = 0; k < KM; ++k) {
            u_ws[(sb + (size_t)k * CD) * NFREQ + f] = u[k];
        }
    }
}

// ---- one radix-2 stage of the 4096-pt inverse FFT; 2 butterflies/thread.
// Butterfly 1: i = tid, twiddle W = (CW,SN) (hoisted).
// Butterfly 2: i = tid+1024; j2 = j1 + 1024/2^s, so its twiddle is
// W * e^{+i*pi/2} = (-SN, CW) — swap/negate (r11-validated derivation).
#define R4KSTAGE(S, SRC, DST, CW, SN) {                                       \
    int j1_ = tid >> (S);                                                     \
    int p1_ = tid + (j1_ << (S));                                             \
    int i2_ = tid + 1024;                                                     \
    int j2_ = i2_ >> (S);                                                     \
    int p2_ = i2_ + (j2_ << (S));                                             \
    float2 A1_ = SRC[SWZ(tid)];                                               \
    float2 B1_ = SRC[SWZ(tid + 2048)];                                        \
    float2 A2_ = SRC[SWZ(i2_)];                                               \
    float2 B2_ = SRC[SWZ(i2_ + 2048)];                                        \
    float2 s1_ = make_float2(A1_.x + B1_.x, A1_.y + B1_.y);                   \
    float2 d1_ = make_float2(A1_.x - B1_.x, A1_.y - B1_.y);                   \
    float2 s2_ = make_float2(A2_.x + B2_.x, A2_.y + B2_.y);                   \
    float2 d2_ = make_float2(A2_.x - B2_.x, A2_.y - B2_.y);                   \
    DST[SWZ(p1_)] = s1_;                                                      \
    DST[SWZ(p1_ + (1 << (S)))] =                                              \
        make_float2(d1_.x * (CW) - d1_.y * (SN),                              \
                    d1_.x * (SN) + d1_.y * (CW));                             \
    DST[SWZ(p2_)] = s2_;                                                      \
    DST[SWZ(p2_ + (1 << (S)))] =                                              \
        make_float2(-d2_.x * (SN) - d2_.y * (CW),                             \
                     d2_.x * (CW) - d2_.y * (SN));                            \
    __syncthreads();                                                          \
}

// Final stage s=11: j = i>>11 = 0 for both butterflies -> twiddle 1.
#define R4KSTAGE11(SRC, DST) {                                                \
    float2 A1_ = SRC[SWZ(tid)];                                               \
    float2 B1_ = SRC[SWZ(tid + 2048)];                                        \
    float2 A2_ = SRC[SWZ(tid + 1024)];                                        \
    float2 B2_ = SRC[SWZ(tid + 3072)];                                        \
    DST[SWZ(tid)]        = make_float2(A1_.x + B1_.x, A1_.y + B1_.y);         \
    DST[SWZ(tid + 2048)] = make_float2(A1_.x - B1_.x, A1_.y - B1_.y);         \
    DST[SWZ(tid + 1024)] = make_float2(A2_.x + B2_.x, A2_.y + B2_.y);         \
    DST[SWZ(tid + 3072)] = make_float2(A2_.x - B2_.x, A2_.y - B2_.y);         \
    __syncthreads();                                                          \
}

// K2: REAL-PAIR inverse FFT. One block per (b,k); 8 passes, each computing TWO
// channels via one 4096-pt complex inverse FFT of Z = Xa + i*Xb:
//  - twiddle-free assembly: Z[j] = (ax-by, ay+bx),
//    Z[4096-j] = conj(Xa)+i*conj(Xb) = (ax+by, bx-ay); xa=Re(z), xb=Im(z)
//  - barriers 224 -> ~112 (r11 counters: VALU 13.8%, HBM 20% — barrier-bound)
//  - 2 independent butterflies/thread/stage (2x ILP)
//  - 11 hoisted sincos (r11-validated), 2nd butterfly twiddle = i*W
//  - val[16][4] + #pragma unroll pass loop = r0/r11 allocator-safe idiom
//  - LDS 2*4096*8 = 65536 B exactly (r2-proven size)
__global__ void __launch_bounds__(1024)
k_inv(const float2* __restrict__ u_ws, float* __restrict__ out)
{
    __shared__ float2 bufA[2 * M_LEN];   // 4096
    __shared__ float2 bufB[2 * M_LEN];   // 4096
    const int tid = threadIdx.x;
    const int bk = blockIdx.x;        // b*8 + k

    // ---- hoisted twiddles: W_s = exp(+i*pi*(tid & ~(2^s-1))/2048), s=0..10 ----
    float cs0,sn0,cs1,sn1,cs2,sn2,cs3,sn3,cs4,sn4,cs5,sn5,cs6,sn6,cs7,sn7,
          cs8,sn8,cs9,sn9,cs10,sn10;
    {
        const float w = (float)M_PI / 2048.0f;
        __sincosf(w * (float)tid,          &sn0,  &cs0);
        __sincosf(w * (float)(tid & ~1),   &sn1,  &cs1);
        __sincosf(w * (float)(tid & ~3),   &sn2,  &cs2);
        __sincosf(w * (float)(tid & ~7),   &sn3,  &cs3);
        __sincosf(w * (float)(tid & ~15),  &sn4,  &cs4);
        __sincosf(w * (float)(tid & ~31),  &sn5,  &cs5);
        __sincosf(w * (float)(tid & ~63),  &sn6,  &cs6);
        __sincosf(w * (float)(tid & ~127), &sn7,  &cs7);
        __sincosf(w * (float)(tid & ~255), &sn8,  &cs8);
        __sincosf(w * (float)(tid & ~511), &sn9,  &cs9);
        __sincosf(w * (float)(tid & ~1023),&sn10, &cs10);
    }

    float val[CD][4];                 // [c][t offset] — r0/r11-proven residency
    const float sc = 1.0f / (float)T_LEN;   // pair-trick scale: 1/4096

    #pragma unroll
    for (int cp = 0; cp < 8; ++cp) {
        const float2* spa = u_ws + (size_t)(bk * CD + 2 * cp) * NFREQ;
        const float2* spb = spa + NFREQ;

        // ---- twiddle-free assembly: Z = Xa + i*Xb, hermitian mirror ----
        #pragma unroll
        for (int jj = 0; jj < 2; ++jj) {
            int j = tid + jj * 1024;
            float2 Xa = spa[j];
            float2 Xb = spb[j];
            if (j > 0) {
                bufA[SWZ(j)]        = make_float2(Xa.x - Xb.y, Xa.y + Xb.x);
                bufA[SWZ(4096 - j)] = make_float2(Xa.x + Xb.y, Xb.x - Xa.y);
            } else {
                bufA[SWZ(0)] = make_float2(Xa.x - Xb.y, Xa.y + Xb.x);
                float2 Na = spa[2048];
                float2 Nb = spb[2048];
                bufA[SWZ(2048)] = make_float2(Na.x - Nb.y, Na.y + Nb.x);
            }
        }
        __syncthreads();

        // ---- 12 unrolled stages, ping-pong A->B->A->...->A ----
        R4KSTAGE(0,  bufA, bufB, cs0,  sn0);
        R4KSTAGE(1,  bufB, bufA, cs1,  sn1);
        R4KSTAGE(2,  bufA, bufB, cs2,  sn2);
        R4KSTAGE(3,  bufB, bufA, cs3,  sn3);
        R4KSTAGE(4,  bufA, bufB, cs4,  sn4);
        R4KSTAGE(5,  bufB, bufA, cs5,  sn5);
        R4KSTAGE(6,  bufA, bufB, cs6,  sn6);
        R4KSTAGE(7,  bufB, bufA, cs7,  sn7);
        R4KSTAGE(8,  bufA, bufB, cs8,  sn8);
        R4KSTAGE(9,  bufB, bufA, cs9,  sn9);
        R4KSTAGE(10, bufA, bufB, cs10, sn10);
        R4KSTAGE11(bufB, bufA);

        // ---- readout: z[4tid+r] -> xa = Re, xb = Im ----
        #pragma unroll
        for (int r = 0; r < 4; ++r) {
            float2 z = bufA[SWZ(4 * tid + r)];
            val[2 * cp + 0][r] = z.x * sc;
            val[2 * cp + 1][r] = z.y * sc;
        }
        __syncthreads();              // before next pass's assembly
    }

    // Each thread owns out[b, k, 4*tid .. 4*tid+3, 0..15]: contiguous 256 B.
    float4* op = (float4*)(out + ((size_t)bk * T_LEN + (size_t)(4 * tid)) * CD);
    #pragma unroll
    for (int r = 0; r < 4; ++r) {
        #pragma unroll
        for (int g = 0; g < 4; ++g) {
            op[r * 4 + g] = make_float4(val[4 * g + 0][r], val[4 * g + 1][r],
                                        val[4 * g + 2][r], val[4 * g + 3][r]);
        }
    }
}

extern "C" void kernel_launch(void* const* d_in, const int* in_sizes, int n_in,
                              void* d_out, int out_size, void* d_ws, size_t ws_size,
                              hipStream_t stream) {
    const float* x         = (const float*)d_in[0];
    const float* log_alpha = (const float*)d_in[1];
    const float* raw_tau   = (const float*)d_in[2];
    const float* raw_omega = (const float*)d_in[3];
    float* out = (float*)d_out;
    float2* u_ws = (float2*)d_ws;   // needs 8192 * 2049 * 8 B = 134.3 MB

    k_fwd_iter<<<dim3(64 * CD), dim3(512), 0, stream>>>(x, log_alpha, raw_tau,
                                                        raw_omega, u_ws);
    k_inv<<<dim3(64 * KM), dim3(1024), 0, stream>>>(u_ws, out);
}